// Round 12
// baseline (130.827 us; speedup 1.0000x reference)
//
#include <hip/hip_runtime.h>
#include <math.h>

#define BB 8
#define CC 64
#define HH 32
#define WW 32
#define HW 1024
#define NEGN 256
#define TEMP 2.0f
#define FACTOR 0.8f
#define EPSF 1e-8f

typedef short bf16x8 __attribute__((ext_vector_type(8)));
typedef float f32x4  __attribute__((ext_vector_type(4)));

__device__ inline unsigned short f2bf(float f) {     // RNE fp32 -> bf16
    unsigned u = __float_as_uint(f);
    u += 0x7FFFu + ((u >> 16) & 1u);
    return (unsigned short)(u >> 16);
}

// workspace: simPart f32[512*256] | sim0Part f32[512] | normq f32[8192] |
//            cnt u32[8] | z2t u16[8*1024*64]
// partials stored (never accumulated). Cross-kernel handoff across the
// dispatch boundary; intra-dispatch cross-block handoff ONLY via the
// fence->device-atomic->fence last-block pattern.

// ---------------------------------------------------------------------------
// K1 prep_z2: ONLY the work that needs a dispatch boundary — convert z2 to
// bf16 TRANSPOSED [q][c] (c contiguous -> 16B MFMA B-frags), fp32 normq
// (ascending-c order, identical to R11), and zero the 8 tail counters.
// ---------------------------------------------------------------------------
__global__ __launch_bounds__(256) void prep_z2(
    const float* __restrict__ z2,      // (B, C, HW)
    unsigned short* __restrict__ z2t,  // (B*1024 rows, 64 c) bf16
    float* __restrict__ normq_ws,      // (B*1024)
    unsigned* __restrict__ cnt)        // (8)
{
    __shared__ float ctile[64 * 16];   // [c][row] fp32, 4 KB

    const int t   = threadIdx.x;
    const int blk = blockIdx.x;        // = b*64 + qtile
    const int b   = blk >> 6;
    const int q0  = (blk & 63) * 16;

    if (blk == 0 && t < 8) cnt[t] = 0;   // zeroed across dispatch boundary

    #pragma unroll
    for (int i = 0; i < 4; ++i) {
        const int idx = t + 256 * i;
        const int c = idx >> 4, row = idx & 15;
        ctile[idx] = z2[((size_t)(b * CC + c)) * HW + q0 + row];
    }
    __syncthreads();

    if (t < 16) {
        float s = 0.f;
        #pragma unroll
        for (int c = 0; c < CC; ++c) { const float v = ctile[c * 16 + t]; s += v * v; }
        normq_ws[b * 1024 + q0 + t] = sqrtf(s);
    }

    unsigned short* dst = z2t + ((size_t)(b * 1024) + q0) * 64;
    ushort4 pk;
    const int o = 4 * t;                 // o = row*64 + c
    pk.x = f2bf(ctile[((o + 0) & 63) * 16 + ((o + 0) >> 6)]);
    pk.y = f2bf(ctile[((o + 1) & 63) * 16 + ((o + 1) >> 6)]);
    pk.z = f2bf(ctile[((o + 2) & 63) * 16 + ((o + 2) >> 6)]);
    pk.w = f2bf(ctile[((o + 3) & 63) * 16 + ((o + 3) >> 6)]);
    *reinterpret_cast<ushort4*>(dst + o) = pk;
}

// ---------------------------------------------------------------------------
// K2 gemm_fused: one block per (b, 16-p tile); everything else fused:
//  (1) issue nidx int2 loads early (p = t>>4, 16 n's each; coalesced)
//  (2) stage nq_s (normq) + z1 ctile into aux; z1sq/z1n fp32 (ascending c,
//      identical order to R11); build bf16 A-frags from ctile (same k-map
//      as the PASSING R11: a0 k=lg*8+j, a1 k=32+lg*8+j)
//  (3) MFMA: wave w owns q in [w*256,(w+1)*256); 2x mfma_f32_16x16x32_bf16
//      per 16x16 tile; cos -> Dt_s (C/D layout per m89)
//  (4) re-alias aux -> imgs (12 KB); weight per p via 16-lane shfl reduce
//  (5) phase B: gather cos, combine, per-n block sums -> simPart store
//  (6) per-b LAST-BLOCK tail: fence -> atomicAdd(cnt[b]) -> last block
//      fences, reduces its 64 partials (ascending pblk) + sim0, and
//      atomicAdds the 3 per-b loss terms into harness-zeroed out[].
// LDS: 64 (Dt_s) + 12 (aux) + ~0.2 KB = 76.4 KB -> 2 blocks/CU; grid 512.
// ---------------------------------------------------------------------------
__global__ __launch_bounds__(256, 2) void gemm_fused(
    const float* __restrict__ z1,             // (B, C, HW)
    const float* __restrict__ img,            // (3, HW)
    const int*   __restrict__ nidx,           // (B, 2, HW, NEG)
    const unsigned short* __restrict__ z2t,   // (B*1024, 64) bf16
    const float* __restrict__ normq_ws,       // (B*1024)
    float* __restrict__ simPart,              // (512, NEG)
    float* __restrict__ sim0Part,             // (512)
    unsigned* __restrict__ cnt,               // (8)
    float* __restrict__ out)                  // (3), harness-zeroed
{
    __shared__ float Dt_s[16 * HW];    // 64 KB: cos, later simpart alias
    __shared__ float aux[3 * HW];      // 12 KB: [nq|ctile|-] -> imgs
    __shared__ float z1n_s[16];
    __shared__ float z1sq_s[16];
    __shared__ float rs[4], rl[4];
    __shared__ int   isLast;

    const int t    = threadIdx.x;
    const int blk  = blockIdx.x;       // = b*64 + ptile
    const int b    = blk >> 6;
    const int p0   = (blk & 63) * 16;
    const int wave = t >> 6;
    const int lane = t & 63;
    const int ln15 = lane & 15;
    const int lg   = lane >> 4;        // k-chunk group 0..3

    // ---- (1) nidx loads FIRST (cold HBM; hide under staging + MFMA) ----
    const int p_b = t >> 4;            // 0..15
    const int tn  = t & 15;
    const size_t nbase = ((size_t)(b * 2) * HW + p0 + p_b) * NEGN;
    const int2* __restrict__ nr = reinterpret_cast<const int2*>(nidx + nbase);
    const int2* __restrict__ nc =
        reinterpret_cast<const int2*>(nidx + nbase + (size_t)HW * NEGN);
    int2 rrv[8], ccv[8];
    #pragma unroll
    for (int j = 0; j < 8; ++j) {
        rrv[j] = nr[tn + 16 * j];
        ccv[j] = nc[tn + 16 * j];
    }

    // ---- (2) stage nq + z1 ctile; norms; A-frags ----
    float* nq_s  = aux;                // [0, 4 KB)
    float* ctile = aux + HW;           // [4 KB, 8 KB)  [c][row]
    reinterpret_cast<float4*>(nq_s)[t] =
        reinterpret_cast<const float4*>(normq_ws + b * 1024)[t];
    #pragma unroll
    for (int i = 0; i < 4; ++i) {
        const int idx = t + 256 * i;
        const int c = idx >> 4, row = idx & 15;
        ctile[idx] = z1[((size_t)(b * CC + c)) * HW + p0 + row];
    }
    __syncthreads();

    if (t < 16) {
        float s = 0.f;
        #pragma unroll
        for (int c = 0; c < CC; ++c) { const float v = ctile[c * 16 + t]; s += v * v; }
        z1sq_s[t] = s; z1n_s[t] = sqrtf(s);
    }
    bf16x8 a0, a1;
    #pragma unroll
    for (int j = 0; j < 8; ++j) {
        a0[j] = (short)f2bf(ctile[(lg * 8 + j) * 16 + ln15]);
        a1[j] = (short)f2bf(ctile[(32 + lg * 8 + j) * 16 + ln15]);
    }
    __syncthreads();                   // z1n_s/z1sq_s visible

    // ---- (3) MFMA over this wave's 16 q-tiles; cos -> Dt_s ----
    const int qw = wave * 256;
    #pragma unroll 4
    for (int tile = 0; tile < 16; ++tile) {
        const int q0t = qw + tile * 16;
        const unsigned short* brow =
            z2t + ((size_t)(b * 1024) + q0t + ln15) * 64 + lg * 8;
        const bf16x8 b0 = *reinterpret_cast<const bf16x8*>(brow);
        const bf16x8 b1 = *reinterpret_cast<const bf16x8*>(brow + 32);
        f32x4 acc = {0.f, 0.f, 0.f, 0.f};
        acc = __builtin_amdgcn_mfma_f32_16x16x32_bf16(a0, b0, acc, 0, 0, 0);
        acc = __builtin_amdgcn_mfma_f32_16x16x32_bf16(a1, b1, acc, 0, 0, 0);

        const float pn = nq_s[q0t + ln15];
        #pragma unroll
        for (int i = 0; i < 4; ++i) {
            const int row = lg * 4 + i;
            Dt_s[row * HW + q0t + ln15] = acc[i] / fmaxf(z1n_s[row] * pn, EPSF);
        }
    }
    __syncthreads();                   // MFMA done; nq/ctile dead

    // ---- (4) re-alias aux -> imgs; weight per p ----
    {
        const float4* __restrict__ imgf4 = reinterpret_cast<const float4*>(img);
        float4* imgs4 = reinterpret_cast<float4*>(aux);
        #pragma unroll
        for (int j = 0; j < 3; ++j) imgs4[t + 256 * j] = imgf4[t + 256 * j];
    }
    __syncthreads();
    float* imgs_l = aux;

    const int pg = p0 + p_b;
    const float cen0 = imgs_l[pg], cen1 = imgs_l[HW + pg], cen2 = imgs_l[2 * HW + pg];
    const float hp = (float)(pg >> 5), wp = (float)(pg & 31);

    int qv[16];
    float se = 0.f, sr = 0.f;
    #pragma unroll
    for (int j = 0; j < 8; ++j) {
        {
            const int q = rrv[j].x * WW + ccv[j].x; qv[2 * j] = q;
            const float dh = hp - (float)rrv[j].x, dw = wp - (float)ccv[j].x;
            se += dh * dh + dw * dw;
            const float d0 = cen0 - imgs_l[q];
            const float d1 = cen1 - imgs_l[HW + q];
            const float d2 = cen2 - imgs_l[2 * HW + q];
            sr += d0 * d0 + d1 * d1 + d2 * d2;
        }
        {
            const int q = rrv[j].y * WW + ccv[j].y; qv[2 * j + 1] = q;
            const float dh = hp - (float)rrv[j].y, dw = wp - (float)ccv[j].y;
            se += dh * dh + dw * dw;
            const float d0 = cen0 - imgs_l[q];
            const float d1 = cen1 - imgs_l[HW + q];
            const float d2 = cen2 - imgs_l[2 * HW + q];
            sr += d0 * d0 + d1 * d1 + d2 * d2;
        }
    }
    #pragma unroll
    for (int off = 8; off; off >>= 1) {      // reduce within the 16-lane p-group
        se += __shfl_xor(se, off);
        sr += __shfl_xor(sr, off);
    }
    const float euc_norm = sqrtf((float)((HH - 1) * (HH - 1) + (WW - 1) * (WW - 1)));
    const float weight = sqrtf(se) / euc_norm * FACTOR +
                         sqrtf(sr) / sqrtf(3.0f) * (1.0f - FACTOR);

    // ---- (5) phase B: gather cos, combine, per-n block sums ----
    float2 sv[8];
    #pragma unroll
    for (int j = 0; j < 8; ++j) {
        const float c0 = Dt_s[p_b * HW + qv[2 * j]];
        const float c1 = Dt_s[p_b * HW + qv[2 * j + 1]];
        sv[j].x = fminf(fabsf(c0 * weight), 1.0f);
        sv[j].y = fminf(fabsf(c1 * weight), 1.0f);
    }
    __syncthreads();                       // Dt_s reads done -> alias safe

    float2* simpart2 = reinterpret_cast<float2*>(Dt_s);  // [16][128]
    #pragma unroll
    for (int j = 0; j < 8; ++j)
        simpart2[p_b * (NEGN / 2) + tn + 16 * j] = sv[j];
    __syncthreads();

    float s = 0.f;
    #pragma unroll
    for (int pp = 0; pp < 16; ++pp) s += Dt_s[pp * NEGN + t];
    simPart[(size_t)blk * NEGN + t] = s;

    if (t == 0) {
        float s0 = 0.f;
        #pragma unroll
        for (int pp = 0; pp < 16; ++pp)
            s0 += fminf(fabsf(z1sq_s[pp] / fmaxf(z1sq_s[pp], EPSF)), 1.0f);
        sim0Part[blk] = s0;
    }

    // ---- (6) per-b last-block tail reduce ----
    __threadfence();                       // release: partials visible
    if (t == 0) isLast = (atomicAdd(&cnt[b], 1u) == 63u);
    __syncthreads();
    if (!isLast) return;
    __threadfence();                       // acquire: other blocks' partials

    float a = 0.f;
    #pragma unroll 8
    for (int pblk = 0; pblk < 64; ++pblk)  // ascending p order
        a += simPart[((size_t)(b * 64 + pblk)) * NEGN + t];

    const float sN = a * (1.0f / HW) * (1.0f / TEMP);
    float ssum = sN;
    float lsum = fmaxf(log1pf(-sN), -100.0f);
    #pragma unroll
    for (int off = 32; off; off >>= 1) {
        ssum += __shfl_down(ssum, off);
        lsum += __shfl_down(lsum, off);
    }
    if ((t & 63) == 0) { rs[t >> 6] = ssum; rl[t >> 6] = lsum; }

    __shared__ float s0sh;
    if (t < 64) {
        float v = sim0Part[b * 64 + t];
        #pragma unroll
        for (int off = 32; off; off >>= 1) v += __shfl_xor(v, off);
        if (t == 0) s0sh = v * (1.0f / HW);
    }
    __syncthreads();

    if (t == 0) {
        const float S = rs[0] + rs[1] + rs[2] + rs[3];
        const float L = rl[0] + rl[1] + rl[2] + rl[3];
        const float s0 = s0sh;
        const float logp = fmaxf(logf(s0), -100.0f);
        atomicAdd(out + 0, -(logp + L) / ((float)(NEGN + 1) * (float)BB));
        atomicAdd(out + 1, s0 / (float)BB);
        atomicAdd(out + 2, S / (float)NEGN * TEMP / (float)BB);
    }
}

extern "C" void kernel_launch(void* const* d_in, const int* in_sizes, int n_in,
                              void* d_out, int out_size, void* d_ws, size_t ws_size,
                              hipStream_t stream) {
    const float* v1   = (const float*)d_in[0];
    const float* v2   = (const float*)d_in[1];
    const float* img  = (const float*)d_in[2];
    const int*   nidx = (const int*)  d_in[3];

    float*    simPart  = (float*)d_ws;                   // 512*256
    float*    sim0Part = simPart + 512 * NEGN;           // 512
    float*    normq_ws = sim0Part + 512;                 // 8192
    unsigned* cnt      = (unsigned*)(normq_ws + 8192);   // 8
    unsigned short* z2t = (unsigned short*)(cnt + 8);    // 512K u16 (1 MB)

    prep_z2<<<512, 256, 0, stream>>>(v2, z2t, normq_ws, cnt);
    gemm_fused<<<512, 256, 0, stream>>>(v1, img, nidx, z2t, normq_ws,
                                        simPart, sim0Part, cnt, (float*)d_out);
}

// Round 13
// 89.756 us; speedup vs baseline: 1.4576x; 1.4576x over previous
//
#include <hip/hip_runtime.h>
#include <math.h>

#define BB 8
#define CC 64
#define HH 32
#define WW 32
#define HW 1024
#define NEGN 256
#define TEMP 2.0f
#define FACTOR 0.8f
#define EPSF 1e-8f

typedef short bf16x8 __attribute__((ext_vector_type(8)));
typedef float f32x4  __attribute__((ext_vector_type(4)));

__device__ inline unsigned short f2bf(float f) {     // RNE fp32 -> bf16
    unsigned u = __float_as_uint(f);
    u += 0x7FFFu + ((u >> 16) & 1u);
    return (unsigned short)(u >> 16);
}

// workspace: simPart f32[512*256] | sim0Part f32[512] | normq f32[8192] |
//            z2t u16[8*1024*64]
// partials stored (never accumulated). ALL cross-block handoff across
// dispatch boundaries (device-coherent); NO in-kernel device fences --
// R12's last-block tail (__threadfence + device atomics from 512 blocks)
// forced per-XCD L2 writebacks and cost ~40us of pure stall.

// ---------------------------------------------------------------------------
// K1 prep_z2: convert z2 to bf16 TRANSPOSED [q][c] (c contiguous -> 16B MFMA
// B-frags) + fp32 normq (ascending-c order). Identical to passing R12.
// ---------------------------------------------------------------------------
__global__ __launch_bounds__(256) void prep_z2(
    const float* __restrict__ z2,      // (B, C, HW)
    unsigned short* __restrict__ z2t,  // (B*1024 rows, 64 c) bf16
    float* __restrict__ normq_ws)      // (B*1024)
{
    __shared__ float ctile[64 * 16];   // [c][row] fp32, 4 KB

    const int t   = threadIdx.x;
    const int blk = blockIdx.x;        // = b*64 + qtile
    const int b   = blk >> 6;
    const int q0  = (blk & 63) * 16;

    #pragma unroll
    for (int i = 0; i < 4; ++i) {
        const int idx = t + 256 * i;
        const int c = idx >> 4, row = idx & 15;
        ctile[idx] = z2[((size_t)(b * CC + c)) * HW + q0 + row];
    }
    __syncthreads();

    if (t < 16) {
        float s = 0.f;
        #pragma unroll
        for (int c = 0; c < CC; ++c) { const float v = ctile[c * 16 + t]; s += v * v; }
        normq_ws[b * 1024 + q0 + t] = sqrtf(s);
    }

    unsigned short* dst = z2t + ((size_t)(b * 1024) + q0) * 64;
    ushort4 pk;
    const int o = 4 * t;                 // o = row*64 + c
    pk.x = f2bf(ctile[((o + 0) & 63) * 16 + ((o + 0) >> 6)]);
    pk.y = f2bf(ctile[((o + 1) & 63) * 16 + ((o + 1) >> 6)]);
    pk.z = f2bf(ctile[((o + 2) & 63) * 16 + ((o + 2) >> 6)]);
    pk.w = f2bf(ctile[((o + 3) & 63) * 16 + ((o + 3) >> 6)]);
    *reinterpret_cast<ushort4*>(dst + o) = pk;
}

// ---------------------------------------------------------------------------
// K2 gemm_fused: identical to R12's kernel with the last-block tail REMOVED
// (sections 1-5 unchanged; simPart/sim0Part are plain stores consumed by the
// reduce_out dispatch). LDS 76.4 KB -> 2 blocks/CU; grid 512 = 2/CU.
// ---------------------------------------------------------------------------
__global__ __launch_bounds__(256, 2) void gemm_fused(
    const float* __restrict__ z1,             // (B, C, HW)
    const float* __restrict__ img,            // (3, HW)
    const int*   __restrict__ nidx,           // (B, 2, HW, NEG)
    const unsigned short* __restrict__ z2t,   // (B*1024, 64) bf16
    const float* __restrict__ normq_ws,       // (B*1024)
    float* __restrict__ simPart,              // (512, NEG)
    float* __restrict__ sim0Part)             // (512)
{
    __shared__ float Dt_s[16 * HW];    // 64 KB: cos, later simpart alias
    __shared__ float aux[3 * HW];      // 12 KB: [nq|ctile|-] -> imgs
    __shared__ float z1n_s[16];
    __shared__ float z1sq_s[16];

    const int t    = threadIdx.x;
    const int blk  = blockIdx.x;       // = b*64 + ptile
    const int b    = blk >> 6;
    const int p0   = (blk & 63) * 16;
    const int wave = t >> 6;
    const int lane = t & 63;
    const int ln15 = lane & 15;
    const int lg   = lane >> 4;        // k-chunk group 0..3

    // ---- (1) nidx loads FIRST (cold HBM; hide under staging + MFMA) ----
    const int p_b = t >> 4;            // 0..15
    const int tn  = t & 15;
    const size_t nbase = ((size_t)(b * 2) * HW + p0 + p_b) * NEGN;
    const int2* __restrict__ nr = reinterpret_cast<const int2*>(nidx + nbase);
    const int2* __restrict__ nc =
        reinterpret_cast<const int2*>(nidx + nbase + (size_t)HW * NEGN);
    int2 rrv[8], ccv[8];
    #pragma unroll
    for (int j = 0; j < 8; ++j) {
        rrv[j] = nr[tn + 16 * j];
        ccv[j] = nc[tn + 16 * j];
    }

    // ---- (2) stage nq + z1 ctile; norms; A-frags ----
    float* nq_s  = aux;                // [0, 4 KB)
    float* ctile = aux + HW;           // [4 KB, 8 KB)  [c][row]
    reinterpret_cast<float4*>(nq_s)[t] =
        reinterpret_cast<const float4*>(normq_ws + b * 1024)[t];
    #pragma unroll
    for (int i = 0; i < 4; ++i) {
        const int idx = t + 256 * i;
        const int c = idx >> 4, row = idx & 15;
        ctile[idx] = z1[((size_t)(b * CC + c)) * HW + p0 + row];
    }
    __syncthreads();

    if (t < 16) {
        float s = 0.f;
        #pragma unroll
        for (int c = 0; c < CC; ++c) { const float v = ctile[c * 16 + t]; s += v * v; }
        z1sq_s[t] = s; z1n_s[t] = sqrtf(s);
    }
    bf16x8 a0, a1;
    #pragma unroll
    for (int j = 0; j < 8; ++j) {
        a0[j] = (short)f2bf(ctile[(lg * 8 + j) * 16 + ln15]);
        a1[j] = (short)f2bf(ctile[(32 + lg * 8 + j) * 16 + ln15]);
    }
    __syncthreads();                   // z1n_s/z1sq_s visible

    // ---- (3) MFMA over this wave's 16 q-tiles; cos -> Dt_s ----
    const int qw = wave * 256;
    #pragma unroll 4
    for (int tile = 0; tile < 16; ++tile) {
        const int q0t = qw + tile * 16;
        const unsigned short* brow =
            z2t + ((size_t)(b * 1024) + q0t + ln15) * 64 + lg * 8;
        const bf16x8 b0 = *reinterpret_cast<const bf16x8*>(brow);
        const bf16x8 b1 = *reinterpret_cast<const bf16x8*>(brow + 32);
        f32x4 acc = {0.f, 0.f, 0.f, 0.f};
        acc = __builtin_amdgcn_mfma_f32_16x16x32_bf16(a0, b0, acc, 0, 0, 0);
        acc = __builtin_amdgcn_mfma_f32_16x16x32_bf16(a1, b1, acc, 0, 0, 0);

        const float pn = nq_s[q0t + ln15];
        #pragma unroll
        for (int i = 0; i < 4; ++i) {
            const int row = lg * 4 + i;
            Dt_s[row * HW + q0t + ln15] = acc[i] / fmaxf(z1n_s[row] * pn, EPSF);
        }
    }
    __syncthreads();                   // MFMA done; nq/ctile dead

    // ---- (4) re-alias aux -> imgs; weight per p ----
    {
        const float4* __restrict__ imgf4 = reinterpret_cast<const float4*>(img);
        float4* imgs4 = reinterpret_cast<float4*>(aux);
        #pragma unroll
        for (int j = 0; j < 3; ++j) imgs4[t + 256 * j] = imgf4[t + 256 * j];
    }
    __syncthreads();
    float* imgs_l = aux;

    const int pg = p0 + p_b;
    const float cen0 = imgs_l[pg], cen1 = imgs_l[HW + pg], cen2 = imgs_l[2 * HW + pg];
    const float hp = (float)(pg >> 5), wp = (float)(pg & 31);

    int qv[16];
    float se = 0.f, sr = 0.f;
    #pragma unroll
    for (int j = 0; j < 8; ++j) {
        {
            const int q = rrv[j].x * WW + ccv[j].x; qv[2 * j] = q;
            const float dh = hp - (float)rrv[j].x, dw = wp - (float)ccv[j].x;
            se += dh * dh + dw * dw;
            const float d0 = cen0 - imgs_l[q];
            const float d1 = cen1 - imgs_l[HW + q];
            const float d2 = cen2 - imgs_l[2 * HW + q];
            sr += d0 * d0 + d1 * d1 + d2 * d2;
        }
        {
            const int q = rrv[j].y * WW + ccv[j].y; qv[2 * j + 1] = q;
            const float dh = hp - (float)rrv[j].y, dw = wp - (float)ccv[j].y;
            se += dh * dh + dw * dw;
            const float d0 = cen0 - imgs_l[q];
            const float d1 = cen1 - imgs_l[HW + q];
            const float d2 = cen2 - imgs_l[2 * HW + q];
            sr += d0 * d0 + d1 * d1 + d2 * d2;
        }
    }
    #pragma unroll
    for (int off = 8; off; off >>= 1) {      // reduce within the 16-lane p-group
        se += __shfl_xor(se, off);
        sr += __shfl_xor(sr, off);
    }
    const float euc_norm = sqrtf((float)((HH - 1) * (HH - 1) + (WW - 1) * (WW - 1)));
    const float weight = sqrtf(se) / euc_norm * FACTOR +
                         sqrtf(sr) / sqrtf(3.0f) * (1.0f - FACTOR);

    // ---- (5) phase B: gather cos, combine, per-n block sums ----
    float2 sv[8];
    #pragma unroll
    for (int j = 0; j < 8; ++j) {
        const float c0 = Dt_s[p_b * HW + qv[2 * j]];
        const float c1 = Dt_s[p_b * HW + qv[2 * j + 1]];
        sv[j].x = fminf(fabsf(c0 * weight), 1.0f);
        sv[j].y = fminf(fabsf(c1 * weight), 1.0f);
    }
    __syncthreads();                       // Dt_s reads done -> alias safe

    float2* simpart2 = reinterpret_cast<float2*>(Dt_s);  // [16][128]
    #pragma unroll
    for (int j = 0; j < 8; ++j)
        simpart2[p_b * (NEGN / 2) + tn + 16 * j] = sv[j];
    __syncthreads();

    float s = 0.f;
    #pragma unroll
    for (int pp = 0; pp < 16; ++pp) s += Dt_s[pp * NEGN + t];
    simPart[(size_t)blk * NEGN + t] = s;

    if (t == 0) {
        float s0 = 0.f;
        #pragma unroll
        for (int pp = 0; pp < 16; ++pp)
            s0 += fminf(fabsf(z1sq_s[pp] / fmaxf(z1sq_s[pp], EPSF)), 1.0f);
        sim0Part[blk] = s0;
    }
}

// ---------------------------------------------------------------------------
// reduce_out: 8 blocks (one per b). Sums 64 p-tile partials per n (ascending
// p), assembles per-b loss terms, atomicAdd into harness-zeroed out[3].
// Identical to the passing R11 kernel.
// ---------------------------------------------------------------------------
__global__ __launch_bounds__(256) void reduce_out(
    const float* __restrict__ simPart,   // (512, NEG)
    const float* __restrict__ sim0Part,  // (512)
    float* __restrict__ out)
{
    const int b = blockIdx.x;
    const int t = threadIdx.x;

    float a = 0.f;
    #pragma unroll 8
    for (int pblk = 0; pblk < 64; ++pblk)
        a += simPart[((size_t)(b * 64 + pblk)) * NEGN + t];

    const float s = a * (1.0f / HW) * (1.0f / TEMP);
    float ssum = s;
    float lsum = fmaxf(log1pf(-s), -100.0f);

    __shared__ float rs[4], rl[4];
    __shared__ float s0sh;
    #pragma unroll
    for (int off = 32; off; off >>= 1) {
        ssum += __shfl_down(ssum, off);
        lsum += __shfl_down(lsum, off);
    }
    if ((t & 63) == 0) { rs[t >> 6] = ssum; rl[t >> 6] = lsum; }

    if (t < 64) {
        float v = sim0Part[b * 64 + t];
        #pragma unroll
        for (int off = 32; off; off >>= 1) v += __shfl_xor(v, off);
        if (t == 0) s0sh = v * (1.0f / HW);
    }
    __syncthreads();

    if (t == 0) {
        const float S = rs[0] + rs[1] + rs[2] + rs[3];
        const float L = rl[0] + rl[1] + rl[2] + rl[3];
        const float s0 = s0sh;
        const float logp = fmaxf(logf(s0), -100.0f);
        atomicAdd(out + 0, -(logp + L) / ((float)(NEGN + 1) * (float)BB));
        atomicAdd(out + 1, s0 / (float)BB);
        atomicAdd(out + 2, S / (float)NEGN * TEMP / (float)BB);
    }
}

extern "C" void kernel_launch(void* const* d_in, const int* in_sizes, int n_in,
                              void* d_out, int out_size, void* d_ws, size_t ws_size,
                              hipStream_t stream) {
    const float* v1   = (const float*)d_in[0];
    const float* v2   = (const float*)d_in[1];
    const float* img  = (const float*)d_in[2];
    const int*   nidx = (const int*)  d_in[3];

    float*    simPart  = (float*)d_ws;                   // 512*256
    float*    sim0Part = simPart + 512 * NEGN;           // 512
    float*    normq_ws = sim0Part + 512;                 // 8192
    unsigned short* z2t = (unsigned short*)(normq_ws + 8192); // 512K u16 (1 MB)

    prep_z2<<<512, 256, 0, stream>>>(v2, z2t, normq_ws);
    gemm_fused<<<512, 256, 0, stream>>>(v1, img, nidx, z2t, normq_ws,
                                        simPart, sim0Part);
    reduce_out<<<BB, 256, 0, stream>>>(simPart, sim0Part, (float*)d_out);
}